// Round 1
// baseline (233.941 us; speedup 1.0000x reference)
//
#include <hip/hip_runtime.h>
#include <math.h>

#define MM 2049
#define BB 16
#define NN 512

static constexpr double D_TWO_PI   = 6.283185307179586476925286766559;
static constexpr float  F_TWO_PI   = 6.28318530717958647692f;
static constexpr float  INV_4TAU   = 83333.33333333333f;   // 1/(4*3e-6)
static constexpr float  PI_OVER_TAU= 1047197.5511965977f;  // pi/tau
static constexpr float  TWO_TAU    = 6.0e-6f;              // 2*tau
static constexpr float  INV_2PI    = 0.15915494309189533f;
static constexpr float  INV_M      = 1.0f / 2049.0f;
static constexpr float  WINF       = 8.0f;

// ---------------------------------------------------------------- spread ----
// red[b][m] = sum_n exp(-(x[b,n]*2pi - 2pi*m/M)^2 / (4 tau)); support ~ +-8 pts
__global__ void k_spread(const float* __restrict__ x, float* __restrict__ red) {
    __shared__ float lred[MM];
    __shared__ float lxg[MM];
    const int b = blockIdx.x;
    for (int m = threadIdx.x; m < MM; m += blockDim.x) {
        lred[m] = 0.0f;
        lxg[m]  = (float)(D_TWO_PI * (double)m / (double)MM);
    }
    __syncthreads();
    for (int n = threadIdx.x; n < NN; n += blockDim.x) {
        float xv = x[b * NN + n];
        float xa = xv * F_TWO_PI;
        float p  = xv * (float)MM;
        int m0 = (int)ceilf(p - WINF);  if (m0 < 0) m0 = 0;
        int m1 = (int)floorf(p + WINF); if (m1 > MM - 1) m1 = MM - 1;
        for (int m = m0; m <= m1; ++m) {
            float d = xa - lxg[m];
            float g = expf(-(d * d) * INV_4TAU);
            atomicAdd(&lred[m], g);
        }
    }
    __syncthreads();
    for (int m = threadIdx.x; m < MM; m += blockDim.x)
        red[b * MM + m] = lred[m];
}

// ----------------------------------------------------------------- DFT 1 ----
// P[b,j] = sum_s red[b,s]*(cos+sin)(2pi js/M)   (= ReF - ImF of fft)
// S[b,j] = sum_s red[b,s]*(cos-sin)(2pi js/M)   (= ReF + ImF)
__global__ void k_dft1(const float* __restrict__ red,
                       float* __restrict__ P, float* __restrict__ S) {
    __shared__ float  lred[MM];
    __shared__ float2 tpm[MM];   // {cos+sin, cos-sin}
    const int b = blockIdx.y;
    const int j = blockIdx.x * blockDim.x + threadIdx.x;
    for (int r = threadIdx.x; r < MM; r += blockDim.x) {
        lred[r] = red[b * MM + r];
        float ang = (float)(D_TWO_PI * (double)r / (double)MM);
        float sn, cs;
        sincosf(ang, &sn, &cs);
        tpm[r] = make_float2(cs + sn, cs - sn);
    }
    __syncthreads();
    if (j >= MM) return;
    float accp = 0.0f, accs = 0.0f;
    int r = 0;
    for (int s = 0; s < MM; ++s) {
        float rv = lred[s];
        float2 t = tpm[r];
        accp = fmaf(rv, t.x, accp);
        accs = fmaf(rv, t.y, accs);
        r += j; if (r >= MM) r -= MM;
    }
    P[b * MM + j] = accp;
    S[b * MM + j] = accs;
}

// ------------------------------------------------------------------- mid ----
// In unshifted fft index j: shifted index msh=(j+1024)%M, k = msh-1024.
// D^2 = (pi/tau)*exp(2 k^2 tau).  Channel swap from ifftshift on axis 1:
//   irfft ch0 <- mix(multRe1, multIm1), ch1 <- mix(multRe0, multIm0).
// a_c = (1/2pi) D^2 mRe_{c'} P ;  bi_c = (1/2pi) D^2 mIm_{c'} S
__global__ void k_mid(const float* __restrict__ P, const float* __restrict__ S,
                      const float* __restrict__ mRe0, const float* __restrict__ mIm0,
                      const float* __restrict__ mRe1, const float* __restrict__ mIm1,
                      float* __restrict__ AB) {
    const int idx = blockIdx.x * blockDim.x + threadIdx.x;
    if (idx >= BB * MM) return;
    const int b = idx / MM;
    const int j = idx - b * MM;
    int msh = j + 1024; if (msh >= MM) msh -= MM;
    const float kf = (float)(msh - 1024);
    const float d2 = PI_OVER_TAU * expf(kf * kf * TWO_TAU);
    const float sc = INV_2PI * d2;
    const float Pv = P[idx], Sv = S[idx];
    float* base = AB + (size_t)b * 4 * MM;
    base[0 * MM + j] = sc * mRe1[msh] * Pv;   // a, channel 0
    base[1 * MM + j] = sc * mRe0[msh] * Pv;   // a, channel 1
    base[2 * MM + j] = sc * mIm1[msh] * Sv;   // b, channel 0
    base[3 * MM + j] = sc * mIm0[msh] * Sv;   // b, channel 1
}

// ----------------------------------------------------------------- DFT 2 ----
// irf[b,c,t] = (1/M) sum_j ( a_c[j] cos(2pi jt/M) - bi_c[j] sin(2pi jt/M) )
__global__ void k_dft2(const float* __restrict__ AB, float* __restrict__ irf) {
    __shared__ float  la0[MM], la1[MM], lb0[MM], lb1[MM];
    __shared__ float2 tcs[MM];   // {cos, sin}
    const int b = blockIdx.y;
    const int t = blockIdx.x * blockDim.x + threadIdx.x;
    const float* base = AB + (size_t)b * 4 * MM;
    for (int r = threadIdx.x; r < MM; r += blockDim.x) {
        la0[r] = base[0 * MM + r];
        la1[r] = base[1 * MM + r];
        lb0[r] = base[2 * MM + r];
        lb1[r] = base[3 * MM + r];
        float ang = (float)(D_TWO_PI * (double)r / (double)MM);
        float sn, cs;
        sincosf(ang, &sn, &cs);
        tcs[r] = make_float2(cs, sn);
    }
    __syncthreads();
    if (t >= MM) return;
    float acc0 = 0.0f, acc1 = 0.0f;
    int r = 0;
    for (int j = 0; j < MM; ++j) {
        float2 cv = tcs[r];
        acc0 = fmaf(la0[j], cv.x, acc0);
        acc0 = fmaf(lb0[j], -cv.y, acc0);
        acc1 = fmaf(la1[j], cv.x, acc1);
        acc1 = fmaf(lb1[j], -cv.y, acc1);
        r += t; if (r >= MM) r -= MM;
    }
    irf[((size_t)b * 2 + 0) * MM + t] = acc0 * INV_M;
    irf[((size_t)b * 2 + 1) * MM + t] = acc1 * INV_M;
}

// ---------------------------------------------------------------- gather ----
// fmm[b,n,c] = (1/M) sum_m g[b,n,m] * irf[b,c,m]  (windowed)
__global__ void k_gather(const float* __restrict__ x, const float* __restrict__ irf,
                         float* __restrict__ out) {
    const int idx = blockIdx.x * blockDim.x + threadIdx.x;  // b*NN + n
    if (idx >= BB * NN) return;
    const int b = idx / NN;
    float xv = x[idx];
    float xa = xv * F_TWO_PI;
    float p  = xv * (float)MM;
    int m0 = (int)ceilf(p - WINF);  if (m0 < 0) m0 = 0;
    int m1 = (int)floorf(p + WINF); if (m1 > MM - 1) m1 = MM - 1;
    const float* i0 = irf + ((size_t)b * 2 + 0) * MM;
    const float* i1 = irf + ((size_t)b * 2 + 1) * MM;
    float acc0 = 0.0f, acc1 = 0.0f;
    for (int m = m0; m <= m1; ++m) {
        float xg = (float)(D_TWO_PI * (double)m / (double)MM);
        float d  = xa - xg;
        float g  = expf(-(d * d) * INV_4TAU);
        acc0 = fmaf(g, i0[m], acc0);
        acc1 = fmaf(g, i1[m], acc1);
    }
    out[idx * 2 + 0] = acc0 * INV_M;
    out[idx * 2 + 1] = acc1 * INV_M;
}

// ---------------------------------------------------------------- launch ----
extern "C" void kernel_launch(void* const* d_in, const int* in_sizes, int n_in,
                              void* d_out, int out_size, void* d_ws, size_t ws_size,
                              hipStream_t stream) {
    const float* x    = (const float*)d_in[0];
    const float* mRe0 = (const float*)d_in[1];
    const float* mIm0 = (const float*)d_in[2];
    const float* mRe1 = (const float*)d_in[3];
    const float* mIm1 = (const float*)d_in[4];
    float* out = (float*)d_out;

    float* ws  = (float*)d_ws;
    float* red = ws;                           // BB*MM
    float* P   = red + (size_t)BB * MM;        // BB*MM
    float* S   = P   + (size_t)BB * MM;        // BB*MM
    float* AB  = S   + (size_t)BB * MM;        // BB*4*MM
    float* irf = AB  + (size_t)BB * 4 * MM;    // BB*2*MM

    k_spread<<<BB, 256, 0, stream>>>(x, red);
    dim3 gdft((MM + 255) / 256, BB);
    k_dft1<<<gdft, 256, 0, stream>>>(red, P, S);
    k_mid<<<(BB * MM + 255) / 256, 256, 0, stream>>>(P, S, mRe0, mIm0, mRe1, mIm1, AB);
    k_dft2<<<gdft, 256, 0, stream>>>(AB, irf);
    k_gather<<<(BB * NN + 255) / 256, 256, 0, stream>>>(x, irf, out);
}

// Round 2
// 99.585 us; speedup vs baseline: 2.3492x; 2.3492x over previous
//
#include <hip/hip_runtime.h>
#include <math.h>

#define MM 2049
#define BB 16
#define NN 512
#define JH 1025            // half-spectrum size (j = 0..1024)
#define SPLIT 8
#define CH1 257            // dft1 sum-chunk: 8*257 = 2056 >= 2049
#define CH2 129            // dft2 sum-chunk: 8*129 = 1032 >= 1025

static constexpr double D_TWO_PI    = 6.283185307179586476925286766559;
static constexpr float  F_TWO_PI    = 6.28318530717958647692f;
static constexpr float  INV_4TAU    = 83333.33333333333f;   // 1/(4*3e-6)
static constexpr float  PI_OVER_TAU = 1047197.5511965977f;  // pi/tau
static constexpr float  TWO_TAU     = 6.0e-6f;              // 2*tau
static constexpr float  INV_2PI     = 0.15915494309189533f;
static constexpr float  INV_M       = 1.0f / 2049.0f;
static constexpr float  WINF        = 8.0f;

// workspace layout (floats)
#define OFF_CS   0                                   // [BB][JH]  sum red*cos
#define OFF_SN   (OFF_CS + BB * JH)                  // [BB][JH]  sum red*sin
#define OFF_IRF  (OFF_SN + BB * JH)                  // [BB][2][MM]
#define OFF_RED  (OFF_IRF + BB * 2 * MM)             // [BB][MM]
#define OFF_AB   (OFF_RED + BB * MM)                 // [BB][JH][4] = {A0,A1,Bd0,Bd1}
#define ZERO_FLOATS OFF_RED                          // CS,SN,IRF need zeroing (atomics)

// ---------------------------------------------------------------- spread ----
__global__ void k_spread(const float* __restrict__ x, float* __restrict__ red) {
    __shared__ float lred[MM];
    __shared__ float lxg[MM];
    const int b = blockIdx.x;
    for (int m = threadIdx.x; m < MM; m += blockDim.x) {
        lred[m] = 0.0f;
        lxg[m]  = (float)(D_TWO_PI * (double)m / (double)MM);
    }
    __syncthreads();
    for (int n = threadIdx.x; n < NN; n += blockDim.x) {
        float xv = x[b * NN + n];
        float xa = xv * F_TWO_PI;
        float p  = xv * (float)MM;
        int m0 = (int)ceilf(p - WINF);  if (m0 < 0) m0 = 0;
        int m1 = (int)floorf(p + WINF); if (m1 > MM - 1) m1 = MM - 1;
        for (int m = m0; m <= m1; ++m) {
            float d = xa - lxg[m];
            float g = expf(-(d * d) * INV_4TAU);
            atomicAdd(&lred[m], g);
        }
    }
    __syncthreads();
    for (int m = threadIdx.x; m < MM; m += blockDim.x)
        red[b * MM + m] = lred[m];
}

// ----------------------------------------------------------------- DFT 1 ----
// CS[b,j] = sum_s red[b,s]*cos(2pi js/M), SN[b,j] = sum_s red[b,s]*sin(...),
// j in [0,1024]. Sum split over blockIdx.z chunks; phase by in-register
// rotation seeded with an exact-integer-mod argument (always < 2pi).
__global__ void k_dft1(const float* __restrict__ red,
                       float* __restrict__ CS, float* __restrict__ SN) {
    __shared__ float lred[CH1];
    const int b  = blockIdx.y;
    const int j  = blockIdx.x * blockDim.x + threadIdx.x;
    const int s0 = blockIdx.z * CH1;
    const int s1 = min(s0 + CH1, MM);
    const int cnt = s1 - s0;
    for (int i = threadIdx.x; i < cnt; i += blockDim.x)
        lred[i] = red[b * MM + s0 + i];
    __syncthreads();
    if (j >= JH) return;
    float ct, st;   // rotation step = e^{i*2pi*j/M}
    {
        float ang = (float)(D_TWO_PI * (double)j / (double)MM);
        __sincosf(ang, &st, &ct);
    }
    float c, s;     // current phase = e^{i*2pi*(j*s)/M}
    {
        int r0 = (j * s0) % MM;
        float ph = (float)(D_TWO_PI * (double)r0 / (double)MM);
        __sincosf(ph, &s, &c);
    }
    float accc = 0.0f, accs = 0.0f;
    for (int i = 0; i < cnt; ++i) {
        float rv = lred[i];
        accc = fmaf(rv, c, accc);
        accs = fmaf(rv, s, accs);
        float t1 = s * st, t2 = s * ct;
        float cn = fmaf(c, ct, -t1);
        float sn = fmaf(c, st,  t2);
        c = cn; s = sn;
    }
    atomicAdd(&CS[b * JH + j], accc);
    atomicAdd(&SN[b * JH + j], accs);
}

// ------------------------------------------------------------------- mid ----
// Folded half-spectrum weights. For j in [0,1024]: msh=j+1024, k=j.
// sc = (1/2pi)*(pi/tau)*exp(2 tau j^2). Channel swap (ifftshift axis 1):
// ch0 <- mult1, ch1 <- mult0.  A = fac*sc*mRe*CS,  Bd = -fac*sc*mIm*SN,
// fac = 2 (1 at j=0).  AB[b][j] = {A0, A1, Bd0, Bd1}.
__global__ void k_mid(const float* __restrict__ CS, const float* __restrict__ SN,
                      const float* __restrict__ mRe0, const float* __restrict__ mIm0,
                      const float* __restrict__ mRe1, const float* __restrict__ mIm1,
                      float* __restrict__ AB) {
    const int idx = blockIdx.x * blockDim.x + threadIdx.x;
    if (idx >= BB * JH) return;
    const int b = idx / JH;
    const int j = idx - b * JH;
    const int msh = j + 1024;
    const float jf = (float)j;
    const float d2 = PI_OVER_TAU * expf(jf * jf * TWO_TAU);
    const float fac = (j == 0) ? 1.0f : 2.0f;
    const float sc = INV_2PI * d2 * fac;
    const float csv = CS[idx], snv = SN[idx];
    float4 v;
    v.x =  sc * mRe1[msh] * csv;   // A  ch0
    v.y =  sc * mRe0[msh] * csv;   // A  ch1
    v.z = -sc * mIm1[msh] * snv;   // Bd ch0
    v.w = -sc * mIm0[msh] * snv;   // Bd ch1
    ((float4*)AB)[idx] = v;
}

// ----------------------------------------------------------------- DFT 2 ----
// irf[b,c,t] = (1/M) * sum_{j=0}^{1024} ( A_c[j] cos(2pi jt/M) - Bd_c[j] sin(...) )
__global__ void k_dft2(const float* __restrict__ AB, float* __restrict__ irf) {
    __shared__ float4 lab[CH2];
    const int b  = blockIdx.y;
    const int t  = blockIdx.x * blockDim.x + threadIdx.x;
    const int j0 = blockIdx.z * CH2;
    const int j1 = min(j0 + CH2, JH);
    const int cnt = j1 - j0;
    const float4* abg = ((const float4*)AB) + (size_t)b * JH;
    for (int i = threadIdx.x; i < cnt; i += blockDim.x)
        lab[i] = abg[j0 + i];
    __syncthreads();
    if (t >= MM) return;
    float ct, st;   // rotation step = e^{i*2pi*t/M}
    {
        float ang = (float)(D_TWO_PI * (double)t / (double)MM);
        __sincosf(ang, &st, &ct);
    }
    float c, s;     // current phase = e^{i*2pi*(t*j)/M}
    {
        int r0 = (t * j0) % MM;
        float ph = (float)(D_TWO_PI * (double)r0 / (double)MM);
        __sincosf(ph, &s, &c);
    }
    float acc0 = 0.0f, acc1 = 0.0f;
    for (int i = 0; i < cnt; ++i) {
        float4 v = lab[i];
        acc0 = fmaf(v.x,  c, acc0);
        acc0 = fmaf(v.z, -s, acc0);
        acc1 = fmaf(v.y,  c, acc1);
        acc1 = fmaf(v.w, -s, acc1);
        float t1 = s * st, t2 = s * ct;
        float cn = fmaf(c, ct, -t1);
        float sn = fmaf(c, st,  t2);
        c = cn; s = sn;
    }
    atomicAdd(&irf[((size_t)b * 2 + 0) * MM + t], acc0 * INV_M);
    atomicAdd(&irf[((size_t)b * 2 + 1) * MM + t], acc1 * INV_M);
}

// ---------------------------------------------------------------- gather ----
__global__ void k_gather(const float* __restrict__ x, const float* __restrict__ irf,
                         float* __restrict__ out) {
    const int idx = blockIdx.x * blockDim.x + threadIdx.x;  // b*NN + n
    if (idx >= BB * NN) return;
    const int b = idx / NN;
    float xv = x[idx];
    float xa = xv * F_TWO_PI;
    float p  = xv * (float)MM;
    int m0 = (int)ceilf(p - WINF);  if (m0 < 0) m0 = 0;
    int m1 = (int)floorf(p + WINF); if (m1 > MM - 1) m1 = MM - 1;
    const float* i0 = irf + ((size_t)b * 2 + 0) * MM;
    const float* i1 = irf + ((size_t)b * 2 + 1) * MM;
    float acc0 = 0.0f, acc1 = 0.0f;
    for (int m = m0; m <= m1; ++m) {
        float xg = (float)(D_TWO_PI * (double)m / (double)MM);
        float d  = xa - xg;
        float g  = expf(-(d * d) * INV_4TAU);
        acc0 = fmaf(g, i0[m], acc0);
        acc1 = fmaf(g, i1[m], acc1);
    }
    out[idx * 2 + 0] = acc0 * INV_M;
    out[idx * 2 + 1] = acc1 * INV_M;
}

// ---------------------------------------------------------------- launch ----
extern "C" void kernel_launch(void* const* d_in, const int* in_sizes, int n_in,
                              void* d_out, int out_size, void* d_ws, size_t ws_size,
                              hipStream_t stream) {
    const float* x    = (const float*)d_in[0];
    const float* mRe0 = (const float*)d_in[1];
    const float* mIm0 = (const float*)d_in[2];
    const float* mRe1 = (const float*)d_in[3];
    const float* mIm1 = (const float*)d_in[4];
    float* out = (float*)d_out;

    float* ws  = (float*)d_ws;
    float* CS  = ws + OFF_CS;
    float* SN  = ws + OFF_SN;
    float* irf = ws + OFF_IRF;
    float* red = ws + OFF_RED;
    float* AB  = ws + OFF_AB;

    // zero the atomic-accumulated buffers (CS, SN, irf are contiguous)
    hipMemsetAsync(ws, 0, (size_t)ZERO_FLOATS * sizeof(float), stream);

    k_spread<<<BB, 256, 0, stream>>>(x, red);
    k_dft1<<<dim3((JH + 255) / 256, BB, SPLIT), 256, 0, stream>>>(red, CS, SN);
    k_mid<<<(BB * JH + 255) / 256, 256, 0, stream>>>(CS, SN, mRe0, mIm0, mRe1, mIm1, AB);
    k_dft2<<<dim3((MM + 255) / 256, BB, SPLIT), 256, 0, stream>>>(AB, irf);
    k_gather<<<(BB * NN + 255) / 256, 256, 0, stream>>>(x, irf, out);
}

// Round 3
// 96.757 us; speedup vs baseline: 2.4178x; 1.0292x over previous
//
#include <hip/hip_runtime.h>
#include <math.h>

#define MM 2049
#define BB 16
#define NN 512
#define JH 1025            // half-spectrum (j = 0..1024)
#define JP 1040            // padded row stride for PSp
#define SZ 8               // s-split in k1
#define SCH 257            // 8*257 = 2056 >= 2049
#define JCH 5              // j-chunks of 256 (5*256 >= 1025)
#define Z2 4               // j-split in k2
#define JB 257             // 4*257 = 1028 >= 1025
#define TCH 9              // t-chunks of 256 (9*256 >= 2049)

static constexpr double D_TWO_PI    = 6.283185307179586476925286766559;
static constexpr double D_STEP      = D_TWO_PI / 2049.0;
static constexpr float  F_TWO_PI    = 6.28318530717958647692f;
static constexpr float  INV_4TAU    = 83333.33333333333f;   // 1/(4*3e-6)
static constexpr float  PI_OVER_TAU = 1047197.5511965977f;  // pi/tau
static constexpr float  TWO_TAU     = 6.0e-6f;              // 2*tau
static constexpr float  INV_2PI     = 0.15915494309189533f;
static constexpr float  INV_M       = 1.0f / 2049.0f;
static constexpr float  WINF        = 8.0f;

// -------------------------------------------------- spread + DFT1 fused ----
// Block (jchunk, b, z): recompute red[s] for s in slice z (LDS, Gaussian
// window +-8), then CS/SN partial sums over that slice for j = jchunk*256+tid.
// Writes PSp[b][z][j] = {sum red*cos, sum red*sin}. No global atomics.
__global__ void k_sdft1(const float* __restrict__ x, float2* __restrict__ PSp) {
    __shared__ float lred[SCH];
    __shared__ float lx[NN];
    const int b  = blockIdx.y;
    const int z  = blockIdx.z;
    const int s0 = z * SCH;
    const int s1 = min(s0 + SCH, MM);
    const int cnt = s1 - s0;
    for (int i = threadIdx.x; i < SCH; i += 256) lred[i] = 0.0f;
    for (int i = threadIdx.x; i < NN;  i += 256) lx[i] = x[b * NN + i];
    __syncthreads();
    for (int n = threadIdx.x; n < NN; n += 256) {
        float xv = lx[n];
        float xa = xv * F_TWO_PI;
        float p  = xv * (float)MM;
        int m0 = (int)ceilf(p - WINF);  if (m0 < s0) m0 = s0;
        int m1 = (int)floorf(p + WINF); if (m1 > s1 - 1) m1 = s1 - 1;
        for (int m = m0; m <= m1; ++m) {
            float xg = (float)((double)m * D_STEP);
            float d  = xa - xg;
            atomicAdd(&lred[m - s0], expf(-(d * d) * INV_4TAU));
        }
    }
    __syncthreads();
    const int j = blockIdx.x * 256 + threadIdx.x;
    if (j >= JH) return;
    float ct, st;   // rotation step e^{i*2pi*j/M}
    { float ang = (float)((double)j * D_STEP); __sincosf(ang, &st, &ct); }
    float c, s;     // phase at s = s0
    { int r0 = (j * s0) % MM; float ph = (float)((double)r0 * D_STEP); __sincosf(ph, &s, &c); }
    float accc = 0.0f, accs = 0.0f;
    for (int i = 0; i < cnt; ++i) {
        float rv = lred[i];                 // LDS broadcast — conflict-free
        accc = fmaf(rv, c, accc);
        accs = fmaf(rv, s, accs);
        float t1 = s * st, t2 = s * ct;
        float cn = fmaf(c, ct, -t1);
        float sn = fmaf(c, st,  t2);
        c = cn; s = sn;
    }
    PSp[((size_t)b * SZ + z) * JP + j] = make_float2(accc, accs);
}

// ---------------------------------------------- mid + DFT2 fused, j-split ----
// Block (tchunk, b, zj): stage weighted AB[j] for j in zj's range (summing the
// 8 s-partials and applying deconv^2 * mult, channel-swapped), then the
// rotation-DFT over that j range for t = tchunk*256+tid.
// Writes irfp[zj][b][c][t] partials. No atomics.
__global__ void k_dft2m(const float2* __restrict__ PSp,
                        const float* __restrict__ mRe0, const float* __restrict__ mIm0,
                        const float* __restrict__ mRe1, const float* __restrict__ mIm1,
                        float* __restrict__ irfp) {
    __shared__ float4 lab[JB];
    const int b   = blockIdx.y;
    const int zj  = blockIdx.z;
    const int jb0 = zj * JB;
    const int jb1 = min(jb0 + JB, JH);
    const int cntj = jb1 - jb0;
    for (int i = threadIdx.x; i < cntj; i += 256) {
        const int j = jb0 + i;
        float cs = 0.0f, sn = 0.0f;
        const float2* base = PSp + (size_t)b * SZ * JP + j;
        #pragma unroll
        for (int z = 0; z < SZ; ++z) {
            float2 ps = base[(size_t)z * JP];
            cs += ps.x; sn += ps.y;
        }
        const int msh = j + 1024;
        const float jf = (float)j;
        const float d2 = PI_OVER_TAU * expf(jf * jf * TWO_TAU);
        const float fac = (j == 0) ? 1.0f : 2.0f;
        const float sc = INV_2PI * d2 * fac;
        float4 v;
        v.x =  sc * mRe1[msh] * cs;   // A  ch0 (channel swap from ifftshift)
        v.y =  sc * mRe0[msh] * cs;   // A  ch1
        v.z = -sc * mIm1[msh] * sn;   // Bd ch0
        v.w = -sc * mIm0[msh] * sn;   // Bd ch1
        lab[i] = v;
    }
    __syncthreads();
    const int t = blockIdx.x * 256 + threadIdx.x;
    if (t >= MM) return;
    float ct, st;   // rotation step e^{i*2pi*t/M}
    { float ang = (float)((double)t * D_STEP); __sincosf(ang, &st, &ct); }
    float c, s;     // phase at j = jb0
    { int r0 = (t * jb0) % MM; float ph = (float)((double)r0 * D_STEP); __sincosf(ph, &s, &c); }
    float acc0 = 0.0f, acc1 = 0.0f;
    for (int i = 0; i < cntj; ++i) {
        float4 v = lab[i];                  // LDS broadcast b128
        acc0 = fmaf(v.x,  c, acc0);
        acc0 = fmaf(v.z, -s, acc0);
        acc1 = fmaf(v.y,  c, acc1);
        acc1 = fmaf(v.w, -s, acc1);
        float t1 = s * st, t2 = s * ct;
        float cn = fmaf(c, ct, -t1);
        float sn2 = fmaf(c, st,  t2);
        c = cn; s = sn2;
    }
    float* o = irfp + ((size_t)(zj * BB + b) * 2) * MM + t;
    o[0]  = acc0 * INV_M;
    o[MM] = acc1 * INV_M;
}

// ---------------------------------------------------------------- gather ----
// fmm[b,n,c] = (1/M) sum_m g[b,n,m] * (sum_zj irfp[zj,b,c,m])  (windowed)
__global__ void k_gather(const float* __restrict__ x, const float* __restrict__ irfp,
                         float* __restrict__ out) {
    const int idx = blockIdx.x * blockDim.x + threadIdx.x;  // b*NN + n
    if (idx >= BB * NN) return;
    const int b = idx / NN;
    float xv = x[idx];
    float xa = xv * F_TWO_PI;
    float p  = xv * (float)MM;
    int m0 = (int)ceilf(p - WINF);  if (m0 < 0) m0 = 0;
    int m1 = (int)floorf(p + WINF); if (m1 > MM - 1) m1 = MM - 1;
    float acc0 = 0.0f, acc1 = 0.0f;
    for (int m = m0; m <= m1; ++m) {
        float xg = (float)((double)m * D_STEP);
        float d  = xa - xg;
        float g  = expf(-(d * d) * INV_4TAU);
        float p0 = 0.0f, p1 = 0.0f;
        #pragma unroll
        for (int z = 0; z < Z2; ++z) {
            const float* base = irfp + ((size_t)(z * BB + b) * 2) * MM;
            p0 += base[m];
            p1 += base[MM + m];
        }
        acc0 = fmaf(g, p0, acc0);
        acc1 = fmaf(g, p1, acc1);
    }
    out[idx * 2 + 0] = acc0 * INV_M;
    out[idx * 2 + 1] = acc1 * INV_M;
}

// ---------------------------------------------------------------- launch ----
extern "C" void kernel_launch(void* const* d_in, const int* in_sizes, int n_in,
                              void* d_out, int out_size, void* d_ws, size_t ws_size,
                              hipStream_t stream) {
    const float* x    = (const float*)d_in[0];
    const float* mRe0 = (const float*)d_in[1];
    const float* mIm0 = (const float*)d_in[2];
    const float* mRe1 = (const float*)d_in[3];
    const float* mIm1 = (const float*)d_in[4];
    float* out = (float*)d_out;

    float2* PSp = (float2*)d_ws;                               // [BB][SZ][JP] float2
    float*  irfp = (float*)d_ws + (size_t)2 * BB * SZ * JP;    // [Z2][BB][2][MM]

    k_sdft1 <<<dim3(JCH, BB, SZ), 256, 0, stream>>>(x, PSp);
    k_dft2m <<<dim3(TCH, BB, Z2), 256, 0, stream>>>(PSp, mRe0, mIm0, mRe1, mIm1, irfp);
    k_gather<<<(BB * NN + 255) / 256, 256, 0, stream>>>(x, irfp, out);
}

// Round 4
// 89.989 us; speedup vs baseline: 2.5997x; 1.0752x over previous
//
#include <hip/hip_runtime.h>
#include <math.h>

#define MM 2049
#define BB 16
#define NN 512
#define JH 1025            // half-spectrum (j = 0..1024)
#define JP 1040            // padded row stride for PSp (float2 units)
#define SZ 8               // s-pair-chunk split in k1
#define PCH 128            // pairs per chunk: 8*128 = 1024 pairs (s=1..1024)
#define JCH 5              // j-chunks of 256 (5*256 >= 1025)
#define Z2 4               // j-split in k2
#define JB2 257            // 4*257 = 1028 >= 1025
#define TCH 5              // t-chunks of 256 (5*256 >= 1025; t in [0,1024])

static constexpr double D_TWO_PI    = 6.283185307179586476925286766559;
static constexpr double D_STEP      = D_TWO_PI / 2049.0;
static constexpr float  F_TWO_PI    = 6.28318530717958647692f;
static constexpr float  INV_4TAU    = 83333.33333333333f;   // 1/(4*3e-6)
static constexpr float  PI_OVER_TAU = 1047197.5511965977f;  // pi/tau
static constexpr float  TWO_TAU     = 6.0e-6f;              // 2*tau
static constexpr float  INV_2PI     = 0.15915494309189533f;
static constexpr float  INV_M       = 1.0f / 2049.0f;
static constexpr float  WINF        = 8.0f;

// ------------------------------------- spread + DFT1 (s-symmetry folded) ----
// Pairs (s, M-s), s in [1,1024]. Block (jchunk, b, z) spreads red over its
// pair ranges A=[a0, a0+127], B=[b0, b0+127] (B is the mirror of A), folds
// into sum/diff, then CS/SN partials for j = jchunk*256+tid via rotation.
// CS[j] += red[0] handled by z==0. PSp[b][z][j] = {CS_part, SN_part}.
__global__ void k_sdft1(const float* __restrict__ x, float2* __restrict__ PSp) {
    __shared__ float  LA[PCH];
    __shared__ float  LB[PCH];
    __shared__ float2 SD[PCH];   // {sum, diff}
    __shared__ float  Lz;        // red[0] (z==0 only)
    const int b  = blockIdx.y;
    const int z  = blockIdx.z;
    const int a0 = 1 + PCH * z;            // A = [a0, a0+PCH-1]  subset of [1,1024]
    const int b0 = 2049 - PCH * (z + 1);   // B = [b0, b0+PCH-1]  mirror (2049-s)
    for (int i = threadIdx.x; i < PCH; i += 256) { LA[i] = 0.0f; LB[i] = 0.0f; }
    if (threadIdx.x == 0) Lz = 0.0f;
    __syncthreads();
    for (int n = threadIdx.x; n < NN; n += 256) {
        float xv = x[b * NN + n];
        float xa = xv * F_TWO_PI;
        float p  = xv * (float)MM;
        int m0 = (int)ceilf(p - WINF);  if (m0 < 0) m0 = 0;
        int m1 = (int)floorf(p + WINF); if (m1 > MM - 1) m1 = MM - 1;
        // coarse skip: window must touch A, B, or (z==0) mesh point 0
        bool hitA = (m1 >= a0) && (m0 <= a0 + PCH - 1);
        bool hitB = (m1 >= b0) && (m0 <= b0 + PCH - 1);
        bool hit0 = (z == 0) && (m0 == 0);
        if (!(hitA || hitB || hit0)) continue;
        for (int m = m0; m <= m1; ++m) {
            float xg = (float)((double)m * D_STEP);
            float d  = xa - xg;
            float g  = expf(-(d * d) * INV_4TAU);
            unsigned ia = (unsigned)(m - a0);
            unsigned ib = (unsigned)(m - b0);
            if (ia < PCH) atomicAdd(&LA[ia], g);
            if (ib < PCH) atomicAdd(&LB[ib], g);
            if (hit0 && m == 0) atomicAdd(&Lz, g);
        }
    }
    __syncthreads();
    // fold: pair of s=a0+i is s'=2049-a0-i = b0 + (PCH-1-i)
    for (int i = threadIdx.x; i < PCH; i += 256) {
        float ra = LA[i], rb = LB[PCH - 1 - i];
        SD[i] = make_float2(ra + rb, ra - rb);
    }
    __syncthreads();
    const int j = blockIdx.x * 256 + threadIdx.x;
    if (j >= JH) return;
    float ct, st;   // rotation step e^{i*2pi*j/M}
    { float ang = (float)((double)j * D_STEP); __sincosf(ang, &st, &ct); }
    float c, s;     // phase at s = a0
    { int r0 = (j * a0) % MM; float ph = (float)((double)r0 * D_STEP); __sincosf(ph, &s, &c); }
    float accc = 0.0f, accs = 0.0f;
    #pragma unroll 4
    for (int i = 0; i < PCH; ++i) {
        float2 sd = SD[i];                  // LDS broadcast b64
        accc = fmaf(sd.x, c, accc);
        accs = fmaf(sd.y, s, accs);
        float t1 = s * st, t2 = s * ct;
        float cn = fmaf(c, ct, -t1);
        float sn = fmaf(c, st,  t2);
        c = cn; s = sn;
    }
    if (z == 0) accc += Lz;                 // s = 0 term (cos=1, sin=0)
    PSp[((size_t)b * SZ + z) * JP + j] = make_float2(accc, accs);
}

// ------------------------------ mid + DFT2 (t-symmetry), j-split partials ----
// Block (tchunk, b, zj): stage weighted AB[j] for its j range (fold the 8
// s-partials, apply deconv^2 * mult channel-swapped), then for t in [0,1024]:
//   E_c = sum A_c cos(2pi jt/M),  O_c = sum Bd_c sin(2pi jt/M)
//   irf_part[t] = (E-O)/M,  irf_part[M-t] = (E+O)/M   (t>=1)
// irfp layout: [zj][b][t][2ch] interleaved for float2 gather loads.
__global__ void k_dft2m(const float2* __restrict__ PSp,
                        const float* __restrict__ mRe0, const float* __restrict__ mIm0,
                        const float* __restrict__ mRe1, const float* __restrict__ mIm1,
                        float* __restrict__ irfp) {
    __shared__ float4 lab[JB2];
    const int b   = blockIdx.y;
    const int zj  = blockIdx.z;
    const int jb0 = zj * JB2;
    const int jb1 = min(jb0 + JB2, JH);
    const int cntj = jb1 - jb0;
    for (int i = threadIdx.x; i < cntj; i += 256) {
        const int j = jb0 + i;
        float cs = 0.0f, sn = 0.0f;
        const float2* base = PSp + (size_t)b * SZ * JP + j;
        #pragma unroll
        for (int z = 0; z < SZ; ++z) {
            float2 ps = base[(size_t)z * JP];
            cs += ps.x; sn += ps.y;
        }
        const int msh = j + 1024;
        const float jf = (float)j;
        const float d2 = PI_OVER_TAU * expf(jf * jf * TWO_TAU);
        const float fac = (j == 0) ? 1.0f : 2.0f;
        const float sc = INV_2PI * d2 * fac;
        float4 v;
        v.x =  sc * mRe1[msh] * cs;   // A  ch0 (channel swap from ifftshift)
        v.y =  sc * mRe0[msh] * cs;   // A  ch1
        v.z = -sc * mIm1[msh] * sn;   // Bd ch0
        v.w = -sc * mIm0[msh] * sn;   // Bd ch1
        lab[i] = v;
    }
    __syncthreads();
    const int t = blockIdx.x * 256 + threadIdx.x;
    if (t >= JH) return;
    float ct, st;   // rotation step e^{i*2pi*t/M}
    { float ang = (float)((double)t * D_STEP); __sincosf(ang, &st, &ct); }
    float c, s;     // phase at j = jb0
    { int r0 = (t * jb0) % MM; float ph = (float)((double)r0 * D_STEP); __sincosf(ph, &s, &c); }
    float E0 = 0.0f, O0 = 0.0f, E1 = 0.0f, O1 = 0.0f;
    #pragma unroll 4
    for (int i = 0; i < cntj; ++i) {
        float4 v = lab[i];                  // LDS broadcast b128
        E0 = fmaf(v.x, c, E0);
        O0 = fmaf(v.z, s, O0);
        E1 = fmaf(v.y, c, E1);
        O1 = fmaf(v.w, s, O1);
        float t1 = s * st, t2 = s * ct;
        float cn = fmaf(c, ct, -t1);
        float sn2 = fmaf(c, st,  t2);
        c = cn; s = sn2;
    }
    float* o = irfp + ((size_t)(zj * BB + b) * MM) * 2;
    o[t * 2 + 0] = (E0 - O0) * INV_M;
    o[t * 2 + 1] = (E1 - O1) * INV_M;
    if (t >= 1) {
        o[(MM - t) * 2 + 0] = (E0 + O0) * INV_M;
        o[(MM - t) * 2 + 1] = (E1 + O1) * INV_M;
    }
}

// ---------------------------------------------------------------- gather ----
// fmm[b,n,c] = (1/M) sum_m g[b,n,m] * (sum_zj irfp[zj,b,m,c])  (windowed)
__global__ void k_gather(const float* __restrict__ x, const float* __restrict__ irfp,
                         float* __restrict__ out) {
    const int idx = blockIdx.x * blockDim.x + threadIdx.x;  // b*NN + n
    if (idx >= BB * NN) return;
    const int b = idx / NN;
    float xv = x[idx];
    float xa = xv * F_TWO_PI;
    float p  = xv * (float)MM;
    int m0 = (int)ceilf(p - WINF);  if (m0 < 0) m0 = 0;
    int m1 = (int)floorf(p + WINF); if (m1 > MM - 1) m1 = MM - 1;
    float acc0 = 0.0f, acc1 = 0.0f;
    for (int m = m0; m <= m1; ++m) {
        float xg = (float)((double)m * D_STEP);
        float d  = xa - xg;
        float g  = expf(-(d * d) * INV_4TAU);
        float p0 = 0.0f, p1 = 0.0f;
        #pragma unroll
        for (int z = 0; z < Z2; ++z) {
            const float2* base = (const float2*)(irfp + ((size_t)(z * BB + b) * MM) * 2);
            float2 v = base[m];
            p0 += v.x;
            p1 += v.y;
        }
        acc0 = fmaf(g, p0, acc0);
        acc1 = fmaf(g, p1, acc1);
    }
    out[idx * 2 + 0] = acc0 * INV_M;
    out[idx * 2 + 1] = acc1 * INV_M;
}

// ---------------------------------------------------------------- launch ----
extern "C" void kernel_launch(void* const* d_in, const int* in_sizes, int n_in,
                              void* d_out, int out_size, void* d_ws, size_t ws_size,
                              hipStream_t stream) {
    const float* x    = (const float*)d_in[0];
    const float* mRe0 = (const float*)d_in[1];
    const float* mIm0 = (const float*)d_in[2];
    const float* mRe1 = (const float*)d_in[3];
    const float* mIm1 = (const float*)d_in[4];
    float* out = (float*)d_out;

    float2* PSp  = (float2*)d_ws;                              // [BB][SZ][JP] float2
    float*  irfp = (float*)d_ws + (size_t)2 * BB * SZ * JP;    // [Z2][BB][MM][2]

    k_sdft1 <<<dim3(JCH, BB, SZ), 256, 0, stream>>>(x, PSp);
    k_dft2m <<<dim3(TCH, BB, Z2), 256, 0, stream>>>(PSp, mRe0, mIm0, mRe1, mIm1, irfp);
    k_gather<<<(BB * NN + 255) / 256, 256, 0, stream>>>(x, irfp, out);
}